// Round 17
// baseline (171.928 us; speedup 1.0000x reference)
//
#include <hip/hip_runtime.h>
#include <hip/hip_bf16.h>

// MDN NLL. N=524288 Dx=128 Dt=64 M=32 K=8.
// R17: TWO-PASS split. R10-R16 plateaued at ~137us because the fused
// kernel needs 16 wave-roles (8 experts x 2 halves + gate + LSE) => 1024
// threads => hard 128-reg cap => 1 block/CU => latency-bound (max pipe 43%).
// Pass 1 (mdn_expert): 512-thr blocks, 8 waves = 4 experts x 2 halves
//   (group = blockIdx&1), bfrag=32 regs, demand ~85 << 128 =>
//   launch_bounds(512,4) => 4 blocks/CU = 32 waves/CU. Writes ll[n][k]
//   (16.8MB f32) to d_ws. Adjacent block pair shares the x-tile stream
//   (2nd read L3-served). Single lgkm barrier/iter, shuffle-free partials,
//   deferred writer waves -- all carried from R13-R16.
// Pass 2 (mdn_gate): gate MFMA + in-lane LSE reading ll coalesced.
//   151MB => ~27us memory-bound at high occupancy.
// Fallback: R16 fused kernel if ws_size < 16.8MB.

#define NN 524288
#define DX 128
#define DT 64
#define MDIM 32
#define KEXP 8

#define T1 512
#define TILE1 32
#define GRID1 2048              // 1024 tile-streams x 2 expert-groups
#define TPB1 16                 // 16384 tiles / 1024 streams

#define T2 512
#define TILE2 128
#define GRID2 1024
#define TPB2 4                  // 4096 tiles / 1024 blocks

#define THREADS 1024            // fallback fused kernel
#define TILE_R 32
#define GRID_MAIN 512
#define TPBF 32

typedef __bf16 bf16x8 __attribute__((ext_vector_type(8)));
typedef float f32x4 __attribute__((ext_vector_type(4)));

__device__ __forceinline__ bf16x8 cvt8(const f32x4 a, const f32x4 b) {
  bf16x8 r;
  r[0] = (__bf16)a[0]; r[1] = (__bf16)a[1]; r[2] = (__bf16)a[2]; r[3] = (__bf16)a[3];
  r[4] = (__bf16)b[0]; r[5] = (__bf16)b[1]; r[6] = (__bf16)b[2]; r[7] = (__bf16)b[3];
  return r;
}

#define MFMA16(a, b, c) __builtin_amdgcn_mfma_f32_16x16x32_bf16(a, b, c, 0, 0, 0)

#define B_LDS() do { \
  asm volatile("s_waitcnt lgkmcnt(0)" ::: "memory"); \
  __builtin_amdgcn_s_barrier(); \
  __builtin_amdgcn_sched_barrier(0); } while (0)

#define HL2PI 0.91893853320467274f

// ============================ PASS 1: experts ============================
__global__ __launch_bounds__(T1, 4) void mdn_expert(
    const float* __restrict__ x, const float* __restrict__ y,
    const float* __restrict__ Wm, const float* __restrict__ bm,
    const float* __restrict__ Wv, const float* __restrict__ bv,
    float* __restrict__ ll_ws)
{
  __shared__ __align__(16) unsigned short xs_l[2][TILE1 * DX];  // 2x8KB
  __shared__ __align__(16) float ys_l[2][TILE1 * MDIM];         // 2x4KB
  __shared__ __align__(16) float llp4[2][TILE1 * 36];           // 2x4.6KB

  const int tid = threadIdx.x;
  const int lane = tid & 63;
  const int wv = tid >> 6;        // 0..7
  const int l15 = lane & 15;
  const int lhi = lane >> 4;
  const int group = blockIdx.x & 1;        // experts group*4 .. +4
  const int stream = blockIdx.x >> 1;
  const int kloc = wv & 3;                 // expert within group
  const int kx = group * 4 + kloc;
  const int hh = wv >> 2;                  // column half

  // staging: x all 512 threads 1 chunk (8 floats); y threads 0-255 (4 floats)
  const int xr = tid >> 4, xsl = tid & 15, xg = xsl ^ (xr & 7);
  const int x_src = xr * DX + xg * 8;
  const int x_dst = xr * 256 + xsl * 16;   // bytes
  const int yr = tid >> 3, ysl = tid & 7, yg = ysl ^ (yr & 7);
  const int y_src = yr * MDIM + yg * 4;
  const int y_dst = yr * 128 + ysl * 16;   // bytes

  f32x4 xa, xb, ya;
  auto issue = [&](int tile) {
    const float* xp = x + (size_t)tile * (TILE1 * DX) + x_src;
    xa = *(const f32x4*)xp;
    xb = *(const f32x4*)(xp + 4);
    if (tid < 256) ya = *(const f32x4*)(y + (size_t)tile * (TILE1 * MDIM) + y_src);
  };
  auto commit = [&](int buf) {
    *(bf16x8*)((char*)xs_l[buf] + x_dst) = cvt8(xa, xb);
    if (tid < 256) *(f32x4*)((char*)ys_l[buf] + y_dst) = ya;
  };

  const int first = stream * TPB1;
  issue(first);

  const f32x4 bmean = *(const f32x4*)&bm[kx * MDIM + hh * 16 + lhi * 4];
  const f32x4 blv   = *(const f32x4*)&bv[kx * MDIM + hh * 16 + lhi * 4];

  // W fragments (transposed MFMA A-operand): ct0 = Wm, ct1 = Wv; 32 regs.
  bf16x8 bfrag[2][4];
  #pragma unroll
  for (int ct = 0; ct < 2; ++ct) {
    const float* W = (ct ? Wv : Wm) + (size_t)kx * (DX * MDIM);
    const int mcol = hh * 16 + l15;
    #pragma unroll
    for (int kk = 0; kk < 4; ++kk) {
      bf16x8 tmp;
      #pragma unroll
      for (int i = 0; i < 8; ++i)
        tmp[i] = (__bf16)W[(kk * 32 + lhi * 8 + i) * MDIM + mcol];
      bfrag[ct][kk] = tmp;
    }
  }

  commit(0);
  B_LDS();

  // deferred ll writer (waves 0-1): sum 8 quadrant partials, store global.
  auto store_ll = [&](int pb, int row0) {
    const int idx = wv * 64 + lane;        // 0..127
    const int rr = idx >> 2, kl = idx & 3;
    const f32x4 pA = *(const f32x4*)&llp4[pb][rr * 36 + kl * 8];
    const f32x4 pB = *(const f32x4*)&llp4[pb][rr * 36 + kl * 8 + 4];
    const float s8 = pA[0] + pA[1] + pA[2] + pA[3]
                   + pB[0] + pB[1] + pB[2] + pB[3];
    ll_ws[(size_t)(row0 + rr) * KEXP + group * 4 + kl] = -(s8 + 32.0f * HL2PI);
  };

  for (int it = 0; it < TPB1; ++it) {
    const int cur = it & 1;
    issue(first + ((it + 1 < TPB1) ? it + 1 : it));

    if (it && wv < 2) store_ll(cur ^ 1, (first + it - 1) * TILE1);

    const unsigned short* xc = xs_l[cur];
    const float* yc = ys_l[cur];
    #pragma unroll
    for (int rt = 0; rt < 2; ++rt) {
      const int rr = rt * 16 + l15;        // sample
      const int r7 = rr & 7;
      f32x4 acc0 = bmean, acc1 = blv;
      #pragma unroll
      for (int kk = 0; kk < 4; ++kk) {
        const int s = (kk * 4 + lhi) ^ r7;
        const bf16x8 af = *(const bf16x8*)((const char*)xc + rr * 256 + s * 16);
        acc0 = MFMA16(bfrag[0][kk], af, acc0);
        acc1 = MFMA16(bfrag[1][kk], af, acc1);
      }
      const int sy = (hh * 4 + lhi) ^ r7;
      const f32x4 y4 = *(const f32x4*)&yc[rr * 32 + sy * 4];
      float part = 0.f;
      #pragma unroll
      for (int j = 0; j < 4; ++j) {
        const float d = y4[j] - acc0[j];
        part += d * d * (0.5f * __expf(-acc1[j])) + 0.5f * acc1[j];
      }
      llp4[cur][rr * 36 + kloc * 8 + hh * 4 + lhi] = part;   // no shuffles
    }

    commit(cur ^ 1);
    B_LDS();          // llp4[cur] + staged buffers visible
  }
  if (wv < 2) store_ll((TPB1 - 1) & 1, (first + TPB1 - 1) * TILE1);
}

// ============================ PASS 2: gate + LSE ============================
__global__ __launch_bounds__(T2, 4) void mdn_gate(
    const float* __restrict__ t, const float* __restrict__ Wg,
    const float* __restrict__ bg, const float* __restrict__ ll_ws,
    float* __restrict__ partials)
{
  __shared__ __align__(16) unsigned short ts_l[2][TILE2 * DT];  // 2x16KB
  __shared__ __align__(16) unsigned short wg_lds[2 * 64 * 8];   // 2KB
  __shared__ float red_s[8];

  const int tid = threadIdx.x;
  const int lane = tid & 63;
  const int wv = tid >> 6;        // 0..7, wave handles samples wv*16..+16
  const int l15 = lane & 15;
  const int lhi = lane >> 4;

  // staging: 1024 chunks (128 rows x 8 chunks of 8 floats); 2 per thread.
  const int c0 = tid, c1 = tid + 512;
  const int r0 = c0 >> 3, s0 = c0 & 7, g0 = s0 ^ (r0 & 7);
  const int r1 = c1 >> 3, s1 = c1 & 7, g1 = s1 ^ (r1 & 7);
  const int t_src0 = r0 * DT + g0 * 8, t_dst0 = r0 * 128 + s0 * 16;
  const int t_src1 = r1 * DT + g1 * 8, t_dst1 = r1 * 128 + s1 * 16;

  f32x4 sa, sb, sc, sd;
  auto issue = [&](int tile) {
    const float* tb = t + (size_t)tile * (TILE2 * DT);
    sa = *(const f32x4*)(tb + t_src0);
    sb = *(const f32x4*)(tb + t_src0 + 4);
    sc = *(const f32x4*)(tb + t_src1);
    sd = *(const f32x4*)(tb + t_src1 + 4);
  };
  auto commit = [&](int buf) {
    *(bf16x8*)((char*)ts_l[buf] + t_dst0) = cvt8(sa, sb);
    *(bf16x8*)((char*)ts_l[buf] + t_dst1) = cvt8(sc, sd);
  };

  const int first = blockIdx.x * TPB2;
  issue(first);

  const f32x4 bgv = *(const f32x4*)&bg[(lhi & 1) * 4];

  if (wv == 7) {
    #pragma unroll
    for (int kk = 0; kk < 2; ++kk) {
      bf16x8 tmp;
      #pragma unroll
      for (int i = 0; i < 8; ++i) {
        const int d = kk * 32 + lhi * 8 + i;
        tmp[i] = (__bf16)((l15 < KEXP) ? Wg[d * KEXP + l15] : 0.f);
      }
      *(bf16x8*)((char*)wg_lds + (kk * 64 + lane) * 16) = tmp;
    }
  }

  commit(0);
  B_LDS();

  float loss_acc = 0.f;

  for (int it = 0; it < TPB2; ++it) {
    const int cur = it & 1;
    issue(first + ((it + 1 < TPB2) ? it + 1 : it));

    const int n0 = (first + it) * TILE2;
    const int rr = wv * 16 + l15;
    const int r7 = rr & 7;

    // ll for this sample, coalesced (lanes cover contiguous 32B/sample)
    const f32x4 lv = *(const f32x4*)&ll_ws[(size_t)(n0 + rr) * KEXP + (lhi & 1) * 4];

    f32x4 g = {0.f, 0.f, 0.f, 0.f};
    #pragma unroll
    for (int kk = 0; kk < 2; ++kk) {
      const int s = (kk * 4 + lhi) ^ r7;
      const bf16x8 tf = *(const bf16x8*)((const char*)ts_l[cur] + rr * 128 + s * 16);
      const bf16x8 wf = *(const bf16x8*)((const char*)wg_lds + (kk * 64 + lane) * 16);
      g = MFMA16(wf, tf, g);
    }
    f32x4 lgv, a4;
    #pragma unroll
    for (int j = 0; j < 4; ++j) {
      lgv[j] = g[j] + bgv[j];    // lanes lhi>=2: garbage, isolated below
      a4[j] = lgv[j] + lv[j];
    }
    float mg = fmaxf(fmaxf(lgv[0], lgv[1]), fmaxf(lgv[2], lgv[3]));
    float ma = fmaxf(fmaxf(a4[0], a4[1]), fmaxf(a4[2], a4[3]));
    mg = fmaxf(mg, __shfl_xor(mg, 16));    // pairs lhi 0<->1 (and 2<->3)
    ma = fmaxf(ma, __shfl_xor(ma, 16));
    float eg = __expf(lgv[0] - mg) + __expf(lgv[1] - mg)
             + __expf(lgv[2] - mg) + __expf(lgv[3] - mg);
    float ea = __expf(a4[0] - ma) + __expf(a4[1] - ma)
             + __expf(a4[2] - ma) + __expf(a4[3] - ma);
    eg += __shfl_xor(eg, 16);
    ea += __shfl_xor(ea, 16);
    if (lhi == 0)
      loss_acc += (mg + __logf(eg)) - (ma + __logf(ea));

    commit(cur ^ 1);
    B_LDS();
  }

  loss_acc += __shfl_xor(loss_acc, 1);
  loss_acc += __shfl_xor(loss_acc, 2);
  loss_acc += __shfl_xor(loss_acc, 4);
  loss_acc += __shfl_xor(loss_acc, 8);
  loss_acc += __shfl_xor(loss_acc, 16);
  loss_acc += __shfl_xor(loss_acc, 32);
  if (lane == 0) red_s[wv] = loss_acc;
  __syncthreads();
  if (tid == 0) {
    float s = 0.f;
    #pragma unroll
    for (int w = 0; w < 8; ++w) s += red_s[w];
    partials[blockIdx.x] = s;
  }
}

// ===================== FALLBACK: R16 fused kernel =====================
__global__ __launch_bounds__(THREADS, 4) void mdn_fused(
    const float* __restrict__ x, const float* __restrict__ t,
    const float* __restrict__ y, const float* __restrict__ Wm,
    const float* __restrict__ bm, const float* __restrict__ Wv,
    const float* __restrict__ bv, const float* __restrict__ Wg,
    const float* __restrict__ bg, float* __restrict__ out_atomic)
{
  __shared__ __align__(16) unsigned short xs_l[2][TILE_R * DX];
  __shared__ __align__(16) unsigned short ts_l[2][TILE_R * DT];
  __shared__ __align__(16) float ys_l[2][TILE_R * MDIM];
  __shared__ __align__(16) unsigned short wg_lds[2 * 64 * 8];
  __shared__ __align__(16) float llp4[2][TILE_R * 68];
  __shared__ __align__(16) float glog[2][TILE_R * 8];
  __shared__ float red_s[16];

  const int tid = threadIdx.x;
  const int lane = tid & 63;
  const int wv = tid >> 6;
  const int l15 = lane & 15;
  const int lhi = lane >> 4;
  const int kx = wv & 7;
  const int hh = wv >> 3;

  int st_ldsoff;
  const float* st_base;
  int st_stride;
  if (tid < 512) {
    const int r = tid >> 4, s = tid & 15, g = s ^ (r & 7);
    st_base = x + (size_t)r * DX + g * 8;
    st_stride = TILE_R * DX;
    st_ldsoff = r * 256 + s * 16;
  } else if (tid < 768) {
    const int u = tid - 512, r = u >> 3, s = u & 7, g = s ^ (r & 7);
    st_base = t + (size_t)r * DT + g * 8;
    st_stride = TILE_R * DT;
    st_ldsoff = r * 128 + s * 16;
  } else {
    const int u = tid - 768, r = u >> 3, s = u & 7, g = s ^ (r & 7);
    st_base = y + (size_t)r * MDIM + g * 4;
    st_stride = TILE_R * MDIM;
    st_ldsoff = r * 128 + s * 16;
  }

  f32x4 sa, sb;
  auto issue = [&](int tile) {
    const float* p = st_base + (size_t)tile * st_stride;
    sa = *(const f32x4*)p;
    if (tid < 768) sb = *(const f32x4*)(p + 4);
  };
  auto commit = [&](int buf) {
    if (tid < 512)      *(bf16x8*)((char*)xs_l[buf] + st_ldsoff) = cvt8(sa, sb);
    else if (tid < 768) *(bf16x8*)((char*)ts_l[buf] + st_ldsoff) = cvt8(sa, sb);
    else                *(f32x4*)((char*)ys_l[buf] + st_ldsoff) = sa;
  };

  const int first = blockIdx.x * TPBF;
  issue(first);

  const f32x4 bmean = *(const f32x4*)&bm[kx * MDIM + hh * 16 + lhi * 4];
  const f32x4 blv   = *(const f32x4*)&bv[kx * MDIM + hh * 16 + lhi * 4];
  f32x4 bgv = {0.f, 0.f, 0.f, 0.f};
  if (wv < 2) bgv = *(const f32x4*)&bg[(lhi & 1) * 4];

  bf16x8 bfrag[2][4];
  #pragma unroll
  for (int ct = 0; ct < 2; ++ct) {
    const float* W = (ct ? Wv : Wm) + (size_t)kx * (DX * MDIM);
    const int mcol = hh * 16 + l15;
    #pragma unroll
    for (int kk = 0; kk < 4; ++kk) {
      bf16x8 tmp;
      #pragma unroll
      for (int i = 0; i < 8; ++i)
        tmp[i] = (__bf16)W[(kk * 32 + lhi * 8 + i) * MDIM + mcol];
      bfrag[ct][kk] = tmp;
    }
  }
  if (wv == 15) {
    #pragma unroll
    for (int kk = 0; kk < 2; ++kk) {
      bf16x8 tmp;
      #pragma unroll
      for (int i = 0; i < 8; ++i) {
        const int d = kk * 32 + lhi * 8 + i;
        tmp[i] = (__bf16)((l15 < KEXP) ? Wg[d * KEXP + l15] : 0.f);
      }
      *(bf16x8*)((char*)wg_lds + (kk * 64 + lane) * 16) = tmp;
    }
  }

  commit(0);
  B_LDS();

  float loss_acc = 0.f;

  auto do_lse = [&](int pb) {
    const int rr = (wv - 4) * 16 + l15;
    const f32x4 lgv = *(const f32x4*)&glog[pb][rr * 8 + (lhi & 1) * 4];
    const int kb = (lhi & 1) * 4;
    f32x4 a4;
    #pragma unroll
    for (int j = 0; j < 4; ++j) {
      const f32x4 pA = *(const f32x4*)&llp4[pb][rr * 68 + (kb + j) * 4];
      const f32x4 pB = *(const f32x4*)&llp4[pb][rr * 68 + 32 + (kb + j) * 4];
      const float s8 = pA[0] + pA[1] + pA[2] + pA[3]
                     + pB[0] + pB[1] + pB[2] + pB[3];
      a4[j] = lgv[j] - s8 - 32.0f * HL2PI;
    }
    float mg = fmaxf(fmaxf(lgv[0], lgv[1]), fmaxf(lgv[2], lgv[3]));
    float ma = fmaxf(fmaxf(a4[0], a4[1]), fmaxf(a4[2], a4[3]));
    mg = fmaxf(mg, __shfl_xor(mg, 16));
    ma = fmaxf(ma, __shfl_xor(ma, 16));
    float eg = __expf(lgv[0] - mg) + __expf(lgv[1] - mg)
             + __expf(lgv[2] - mg) + __expf(lgv[3] - mg);
    float ea = __expf(a4[0] - ma) + __expf(a4[1] - ma)
             + __expf(a4[2] - ma) + __expf(a4[3] - ma);
    eg += __shfl_xor(eg, 16);
    ea += __shfl_xor(ea, 16);
    if (lhi == 0)
      loss_acc += (mg + __logf(eg)) - (ma + __logf(ea));
  };

  for (int it = 0; it < TPBF; ++it) {
    const int cur = it & 1;
    issue(first + ((it + 1 < TPBF) ? it + 1 : it));
    if (it && (wv == 4 || wv == 5)) do_lse(cur ^ 1);

    if (wv < 2) {
      const int rr = wv * 16 + l15;
      const int r7 = rr & 7;
      f32x4 g = {0.f, 0.f, 0.f, 0.f};
      #pragma unroll
      for (int kk = 0; kk < 2; ++kk) {
        const int s = (kk * 4 + lhi) ^ r7;
        const bf16x8 tf = *(const bf16x8*)((const char*)ts_l[cur] + rr * 128 + s * 16);
        const bf16x8 wf = *(const bf16x8*)((const char*)wg_lds + (kk * 64 + lane) * 16);
        g = MFMA16(wf, tf, g);
      }
      if (lhi < 2) {
        f32x4 lg;
        #pragma unroll
        for (int j = 0; j < 4; ++j) lg[j] = g[j] + bgv[j];
        *(f32x4*)&glog[cur][rr * 8 + lhi * 4] = lg;
      }
    }

    const unsigned short* xc = xs_l[cur];
    const float* yc = ys_l[cur];
    #pragma unroll
    for (int rt = 0; rt < 2; ++rt) {
      const int rr = rt * 16 + l15;
      const int r7 = rr & 7;
      f32x4 acc0 = bmean, acc1 = blv;
      #pragma unroll
      for (int kk = 0; kk < 4; ++kk) {
        const int s = (kk * 4 + lhi) ^ r7;
        const bf16x8 af = *(const bf16x8*)((const char*)xc + rr * 256 + s * 16);
        acc0 = MFMA16(bfrag[0][kk], af, acc0);
        acc1 = MFMA16(bfrag[1][kk], af, acc1);
      }
      const int sy = (hh * 4 + lhi) ^ r7;
      const f32x4 y4 = *(const f32x4*)&yc[rr * 32 + sy * 4];
      float part = 0.f;
      #pragma unroll
      for (int j = 0; j < 4; ++j) {
        const float d = y4[j] - acc0[j];
        part += d * d * (0.5f * __expf(-acc1[j])) + 0.5f * acc1[j];
      }
      llp4[cur][rr * 68 + hh * 32 + kx * 4 + lhi] = part;
    }

    commit(cur ^ 1);
    B_LDS();
  }
  if (wv == 4 || wv == 5) do_lse((TPBF - 1) & 1);

  loss_acc += __shfl_xor(loss_acc, 1);
  loss_acc += __shfl_xor(loss_acc, 2);
  loss_acc += __shfl_xor(loss_acc, 4);
  loss_acc += __shfl_xor(loss_acc, 8);
  loss_acc += __shfl_xor(loss_acc, 16);
  loss_acc += __shfl_xor(loss_acc, 32);
  if (lane == 0) red_s[wv] = loss_acc;
  __syncthreads();
  if (tid == 0) {
    float s = 0.f;
    #pragma unroll
    for (int w = 0; w < 16; ++w) s += red_s[w];
    atomicAdd(out_atomic, s);
  }
}

// ===================== shared reduction kernels =====================
__global__ void mdn_reg(const float* __restrict__ Wm, const float* __restrict__ Wv,
                        const float* __restrict__ Wg, float* __restrict__ partials,
                        float* __restrict__ out_atomic)
{
  __shared__ float red[4];
  const int gid = blockIdx.x * 256 + threadIdx.x;
  const int stride = 64 * 256;
  float s = 0.f;
  for (int i = gid; i < DX * MDIM * KEXP; i += stride) { float w = Wm[i]; s += w * w; }
  for (int i = gid; i < DX * MDIM * KEXP; i += stride) { float w = Wv[i]; s += w * w; }
  for (int i = gid; i < DT * KEXP; i += stride)        { float w = Wg[i]; s += w * w; }
  s += __shfl_xor(s, 1);
  s += __shfl_xor(s, 2);
  s += __shfl_xor(s, 4);
  s += __shfl_xor(s, 8);
  s += __shfl_xor(s, 16);
  s += __shfl_xor(s, 32);
  if ((threadIdx.x & 63) == 0) red[threadIdx.x >> 6] = s;
  __syncthreads();
  if (threadIdx.x == 0) {
    float b = red[0] + red[1] + red[2] + red[3];
    if (partials) partials[GRID2 + blockIdx.x] = b;
    else atomicAdd(out_atomic, b);
  }
}

__global__ void mdn_final(const float* __restrict__ partials, float* __restrict__ out)
{
  __shared__ float red[4];
  float s = 0.f;
  for (int i = threadIdx.x; i < GRID2 + 64; i += 256) s += partials[i];
  s += __shfl_xor(s, 1);
  s += __shfl_xor(s, 2);
  s += __shfl_xor(s, 4);
  s += __shfl_xor(s, 8);
  s += __shfl_xor(s, 16);
  s += __shfl_xor(s, 32);
  if ((threadIdx.x & 63) == 0) red[threadIdx.x >> 6] = s;
  __syncthreads();
  if (threadIdx.x == 0) out[0] = red[0] + red[1] + red[2] + red[3];
}

extern "C" void kernel_launch(void* const* d_in, const int* in_sizes, int n_in,
                              void* d_out, int out_size, void* d_ws, size_t ws_size,
                              hipStream_t stream)
{
  const float* x  = (const float*)d_in[0];
  const float* t  = (const float*)d_in[1];
  const float* y  = (const float*)d_in[2];
  const float* Wm = (const float*)d_in[3];
  const float* bm = (const float*)d_in[4];
  const float* Wv = (const float*)d_in[5];
  const float* bv = (const float*)d_in[6];
  const float* Wg = (const float*)d_in[7];
  const float* bg = (const float*)d_in[8];
  float* out = (float*)d_out;

  const size_t ws_need = ((size_t)NN * KEXP + GRID2 + 64) * sizeof(float);
  if (ws_size >= ws_need) {
    float* ll_ws = (float*)d_ws;
    float* partials = ll_ws + (size_t)NN * KEXP;
    mdn_expert<<<GRID1, T1, 0, stream>>>(x, y, Wm, bm, Wv, bv, ll_ws);
    mdn_gate<<<GRID2, T2, 0, stream>>>(t, Wg, bg, ll_ws, partials);
    mdn_reg<<<64, 256, 0, stream>>>(Wm, Wv, Wg, partials, nullptr);
    mdn_final<<<1, 256, 0, stream>>>(partials, out);
  } else {
    hipMemsetAsync(out, 0, sizeof(float), stream);
    mdn_fused<<<GRID_MAIN, THREADS, 0, stream>>>(x, t, y, Wm, bm, Wv, bv, Wg, bg, out);
    mdn_reg<<<64, 256, 0, stream>>>(Wm, Wv, Wg, nullptr, out);
  }
}